// Round 3
// baseline (1073.476 us; speedup 1.0000x reference)
//
#include <hip/hip_runtime.h>

// ---------------------------------------------------------------------------
// MHSA (faithful: softmax over HEADS at each position).
//   Q/K/V proj: 256x256 8-wave 4-phase MFMA GEMM, fp32-A fused convert (reg-staged)
//   out proj  : same structure, bf16 A via global_load_lds
//   attention : per-position 16x16 softmax-over-heads + PV, permuted scatter
// ---------------------------------------------------------------------------

#define DEV __device__ __forceinline__

using short8  = __attribute__((ext_vector_type(8))) short;
using ushort8 = __attribute__((ext_vector_type(8))) unsigned short;
using f32x4   = __attribute__((ext_vector_type(4))) float;
using u16x8   = __attribute__((ext_vector_type(8))) unsigned short;

constexpr int BATCH = 4, SEQ = 4096, DIM = 2048;
constexpr int GM = BATCH * SEQ;   // 16384
constexpr int GN = DIM, GK = DIM; // 2048

DEV unsigned short f2bf(float f) {
  unsigned int u = __builtin_bit_cast(unsigned int, f);
  u += 0x7FFFu + ((u >> 16) & 1u);   // RNE
  return (unsigned short)(u >> 16);
}
DEV float bf2f(unsigned short h) {
  unsigned int u = ((unsigned int)h) << 16;
  return __builtin_bit_cast(float, u);
}

DEV void gload16(const void* g, void* l) {
  __builtin_amdgcn_global_load_lds(
      (const __attribute__((address_space(1))) void*)g,
      (__attribute__((address_space(3))) void*)l, 16, 0, 0);
}

#define BAR      __builtin_amdgcn_s_barrier()
#define LGKM0    asm volatile("s_waitcnt lgkmcnt(0)" ::: "memory")
#define LGKM(N)  asm volatile("s_waitcnt lgkmcnt(" #N ")" ::: "memory")
#define VMC(N)   asm volatile("s_waitcnt vmcnt(" #N ")" ::: "memory")
#define SCHED0   __builtin_amdgcn_sched_barrier(0)
#define MFMA16(a, b, c) __builtin_amdgcn_mfma_f32_16x16x32_bf16(a, b, c, 0, 0, 0)

// ---------------- fp32 -> bf16 conversion (weights only) ------------------
__global__ void cvt_f32_bf16(const float* __restrict__ src,
                             unsigned short* __restrict__ dst, int n) {
  int i = (blockIdx.x * blockDim.x + threadIdx.x) * 4;
  if (i >= n) return;
  f32x4 f = *(const f32x4*)(src + i);
  ushort4 o;
  o.x = f2bf(f[0]); o.y = f2bf(f[1]); o.z = f2bf(f[2]); o.w = f2bf(f[3]);
  *(ushort4*)(dst + i) = o;
}

// ---------------- 256^2 8-wave 4-phase GEMM: C = A[M,K] * B[N,K]^T + bias --
// LDS: 2x(A 256x64 + B 256x64) bf16 = 128 KiB, XOR-swizzled (byte^=(row&7)<<4).
// AF32: A read as fp32, converted in-register, ds_write'd (fused convert).
template <bool AF32, bool OUTF32>
__global__ __launch_bounds__(512, 2)
void gemm256(const void* __restrict__ Ap_,
             const unsigned short* __restrict__ Bp,
             const float* __restrict__ bias, void* __restrict__ Cp) {
  constexpr int BK = 64, KT = GK / BK;   // 32 K-tiles
  __shared__ unsigned short As[2][256 * BK];
  __shared__ unsigned short Bs[2][256 * BK];

  const float* Af          = (const float*)Ap_;
  const unsigned short* A16 = (const unsigned short*)Ap_;

  const int tid  = threadIdx.x;
  const int lane = tid & 63;
  const int wv   = tid >> 6;
  const int wm   = wv >> 2, wn = wv & 3;

  // XCD-chunked mapping: xcd = bid&7 owns mt stripe [xcd*8, xcd*8+8);
  // within stripe, concurrent window = 4mt x 8nt (A shared 8-way, B 4-way in L2).
  int bid = (int)blockIdx.x;
  const int xcd = bid & 7, rr = bid >> 3;
  const int gg = rr >> 5, jj = rr & 31;
  const int mt = xcd * 8 + gg * 4 + (jj & 3);
  const int nt = jj >> 2;
  const int bm0 = mt * 256, bn0 = nt * 256;

  // staging geometry: dest byte d (linear), source elem = unswizzle(d)
  const int dst0 = tid * 16;
  int offA[4], offB[4];
#pragma unroll
  for (int r = 0; r < 4; ++r) {
    int d = dst0 + r * 8192;
    int s = d ^ (((d >> 7) & 7) << 4);
    int row = s >> 7, col = (s & 127) >> 1;
    offA[r] = (bm0 + row) * GK + col;
    offB[r] = (bn0 + row) * GK + col;
  }

  const int r16 = lane & 15, kb = (lane >> 4) * 16;
  const int arow = wm * 128 + r16;
  const int brow = wn * 64 + r16;

  f32x4 acc[8][4] = {};
  short8 af[4][2], bl[2][2], bh[2][2];
  f32x4 areg[2][2];

  auto stA16 = [&](int buf, int kt, int r) {
    gload16(A16 + (size_t)offA[r] + (size_t)kt * BK,
            (char*)&As[buf][0] + (dst0 + r * 8192));
  };
  auto stB = [&](int buf, int kt, int r) {
    gload16(Bp + (size_t)offB[r] + (size_t)kt * BK,
            (char*)&Bs[buf][0] + (dst0 + r * 8192));
  };
  auto ldA32 = [&](int kt, int r, int slot) {
    const float* ga = Af + (size_t)offA[r] + (size_t)kt * BK;
    areg[slot][0] = *(const f32x4*)ga;
    areg[slot][1] = *(const f32x4*)(ga + 4);
  };
  auto wrA = [&](int buf, int r, int slot) {
    ushort8 p;
#pragma unroll
    for (int q = 0; q < 4; ++q) {
      p[q]     = f2bf(areg[slot][0][q]);
      p[4 + q] = f2bf(areg[slot][1][q]);
    }
    *(ushort8*)((char*)&As[buf][0] + (dst0 + r * 8192)) = p;
  };
  auto ldf = [&](const unsigned short* base, int row, int ks) -> short8 {
    int a = (row * 128 + ks * 64 + kb) ^ ((row & 7) << 4);
    return *(const short8*)((const char*)base + a);
  };

  // ---- prologue ----
  if constexpr (AF32) {
    f32x4 t0[4][2];
#pragma unroll
    for (int r = 0; r < 4; ++r) {
      const float* ga = Af + (size_t)offA[r];
      t0[r][0] = *(const f32x4*)ga;
      t0[r][1] = *(const f32x4*)(ga + 4);
    }
    SCHED0;
#pragma unroll
    for (int r = 0; r < 4; ++r) stB(0, 0, r);
    SCHED0; VMC(4); SCHED0;            // 8 A-loads done; 4 B-gloads in flight
#pragma unroll
    for (int r = 0; r < 4; ++r) {
      ushort8 p;
#pragma unroll
      for (int q = 0; q < 4; ++q) {
        p[q] = f2bf(t0[r][0][q]); p[4 + q] = f2bf(t0[r][1][q]);
      }
      *(ushort8*)((char*)&As[0][0] + (dst0 + r * 8192)) = p;
    }
    SCHED0; VMC(0); LGKM0;
    BAR;
  } else {
#pragma unroll
    for (int r = 0; r < 4; ++r) stA16(0, 0, r);
#pragma unroll
    for (int r = 0; r < 4; ++r) stB(0, 0, r);
#pragma unroll
    for (int r = 0; r < 4; ++r) stA16(1, 1, r);
    VMC(4);                             // A(0)+B(0) resident; A(1) in flight
    BAR;
  }

  for (int kt = 0; kt < KT; ++kt) {
    const int cb = kt & 1, nb = cb ^ 1;
    const unsigned short* Ab = &As[cb][0];
    const unsigned short* Bb = &Bs[cb][0];
    const bool more = (kt + 1 < KT);

    // ===== Phase 0: Q(mlo,nlo), k-split =====
    if constexpr (AF32) {
      if (more) {
        ldA32(kt + 1, 0, 0); ldA32(kt + 1, 1, 1);
        SCHED0;
        stB(nb, kt + 1, 0); stB(nb, kt + 1, 1);
        SCHED0;
      }
    } else {
      if (more) { stB(nb, kt + 1, 0); stB(nb, kt + 1, 1); }
    }
#pragma unroll
    for (int m = 0; m < 4; ++m) af[m][0] = ldf(Ab, arow + m * 16, 0);
#pragma unroll
    for (int n = 0; n < 2; ++n) bl[n][0] = ldf(Bb, brow + n * 16, 0);
    SCHED0;
#pragma unroll
    for (int m = 0; m < 4; ++m) af[m][1] = ldf(Ab, arow + m * 16, 1);
#pragma unroll
    for (int n = 0; n < 2; ++n) bl[n][1] = ldf(Bb, brow + n * 16, 1);
    BAR;
    LGKM(6); SCHED0;
    __builtin_amdgcn_s_setprio(1);
#pragma unroll
    for (int m = 0; m < 4; ++m)
#pragma unroll
      for (int n = 0; n < 2; ++n)
        acc[m][n] = MFMA16(af[m][0], bl[n][0], acc[m][n]);
    LGKM0; SCHED0;
#pragma unroll
    for (int m = 0; m < 4; ++m)
#pragma unroll
      for (int n = 0; n < 2; ++n)
        acc[m][n] = MFMA16(af[m][1], bl[n][1], acc[m][n]);
    __builtin_amdgcn_s_setprio(0);
    BAR;

    // ===== Phase 1: Q(mlo,nhi) =====
    if constexpr (AF32) {
      if (more) {
        SCHED0; VMC(2); SCHED0;        // A01 done (B01 may fly)
        wrA(nb, 0, 0); wrA(nb, 1, 1);
        ldA32(kt + 1, 2, 0); ldA32(kt + 1, 3, 1);
        SCHED0;
        stB(nb, kt + 1, 2); stB(nb, kt + 1, 3);
        SCHED0;
      }
    } else {
      if (more) { stB(nb, kt + 1, 2); stB(nb, kt + 1, 3); }
    }
#pragma unroll
    for (int n = 0; n < 2; ++n) {
      bh[n][0] = ldf(Bb, brow + 32 + n * 16, 0);
      bh[n][1] = ldf(Bb, brow + 32 + n * 16, 1);
    }
    BAR;
    LGKM0; SCHED0;
    __builtin_amdgcn_s_setprio(1);
#pragma unroll
    for (int m = 0; m < 4; ++m)
#pragma unroll
      for (int n = 0; n < 2; ++n) {
        acc[m][2 + n] = MFMA16(af[m][0], bh[n][0], acc[m][2 + n]);
        acc[m][2 + n] = MFMA16(af[m][1], bh[n][1], acc[m][2 + n]);
      }
    __builtin_amdgcn_s_setprio(0);
    BAR;

    // ===== Phase 2: Q(mhi,nhi) =====
    if constexpr (AF32) {
      if (more) {
        SCHED0; VMC(2); SCHED0;        // drains B01+A23, leaves B23
        wrA(nb, 2, 0); wrA(nb, 3, 1);
      }
    } else {
      if (kt + 2 < KT) { stA16(cb, kt + 2, 0); stA16(cb, kt + 2, 2); }
    }
#pragma unroll
    for (int m = 0; m < 4; ++m) {
      af[m][0] = ldf(Ab, arow + 64 + m * 16, 0);
      af[m][1] = ldf(Ab, arow + 64 + m * 16, 1);
    }
    BAR;
    LGKM0; SCHED0;
    __builtin_amdgcn_s_setprio(1);
#pragma unroll
    for (int m = 0; m < 4; ++m)
#pragma unroll
      for (int n = 0; n < 2; ++n) {
        acc[4 + m][2 + n] = MFMA16(af[m][0], bh[n][0], acc[4 + m][2 + n]);
        acc[4 + m][2 + n] = MFMA16(af[m][1], bh[n][1], acc[4 + m][2 + n]);
      }
    __builtin_amdgcn_s_setprio(0);
    BAR;

    // ===== Phase 3: Q(mhi,nlo) =====
    if constexpr (AF32) {
      SCHED0; VMC(0); SCHED0;          // B23 done -> nb complete
    } else {
      if (kt + 2 < KT) { stA16(cb, kt + 2, 1); stA16(cb, kt + 2, 3); }
      SCHED0; VMC(4); SCHED0;          // drain A(kt+1)+B(kt+1); A(kt+2) flies
    }
    BAR;
    __builtin_amdgcn_s_setprio(1);
#pragma unroll
    for (int m = 0; m < 4; ++m)
#pragma unroll
      for (int n = 0; n < 2; ++n) {
        acc[4 + m][n] = MFMA16(af[m][0], bl[n][0], acc[4 + m][n]);
        acc[4 + m][n] = MFMA16(af[m][1], bl[n][1], acc[4 + m][n]);
      }
    __builtin_amdgcn_s_setprio(0);
    BAR;
  }

  // ---- epilogue: C row=(lane>>4)*4+i, col=lane&15 (m89-verified) ----
  float bs[4];
#pragma unroll
  for (int n = 0; n < 4; ++n) bs[n] = bias[bn0 + wn * 64 + n * 16 + r16];
  const int rb = (lane >> 4) * 4;
#pragma unroll
  for (int m = 0; m < 8; ++m)
#pragma unroll
    for (int i = 0; i < 4; ++i) {
      const size_t row = (size_t)bm0 + wm * 128 + m * 16 + rb + i;
#pragma unroll
      for (int n = 0; n < 4; ++n) {
        const int col = bn0 + wn * 64 + n * 16 + r16;
        float v = acc[m][n][i] + bs[n];
        if constexpr (OUTF32)
          ((float*)Cp)[row * GN + col] = v;
        else
          ((unsigned short*)Cp)[row * GN + col] = f2bf(v);
      }
    }
}

// ---------------- per-position attention (softmax over heads) -------------
__global__ __launch_bounds__(256)
void attn_kernel(const unsigned short* __restrict__ Qb,
                 const unsigned short* __restrict__ Kb,
                 const unsigned short* __restrict__ Vb,
                 float* __restrict__ attnOut,
                 unsigned short* __restrict__ X2) {
  __shared__ float qf[16 * 128];
  __shared__ float kf[16 * 132];
  __shared__ float vf[16 * 128];
  __shared__ float sc[256];

  const int t = threadIdx.x;
  const int p = blockIdx.x;
  const size_t rowoff = (size_t)p * DIM;

  {
    const int e = t * 8;
    u16x8 qv = *(const u16x8*)(Qb + rowoff + e);
    u16x8 kv = *(const u16x8*)(Kb + rowoff + e);
    u16x8 vv = *(const u16x8*)(Vb + rowoff + e);
    const int r = t >> 4, c = (t & 15) * 8;
#pragma unroll
    for (int j = 0; j < 8; ++j) qf[r * 128 + c + j] = bf2f(qv[j]);
#pragma unroll
    for (int j = 0; j < 8; ++j) kf[r * 132 + c + j] = bf2f(kv[j]);
#pragma unroll
    for (int j = 0; j < 8; ++j) vf[r * 128 + c + j] = bf2f(vv[j]);
  }
  __syncthreads();

  const int i = t >> 4, j = t & 15;
  float s = 0.f;
#pragma unroll
  for (int d4 = 0; d4 < 32; ++d4) {
    f32x4 q4 = *(const f32x4*)&qf[i * 128 + d4 * 4];
    f32x4 k4 = *(const f32x4*)&kf[j * 132 + d4 * 4];
    s = fmaf(q4[0], k4[0], fmaf(q4[1], k4[1], fmaf(q4[2], k4[2], fmaf(q4[3], k4[3], s))));
  }
  s *= 0.08838834764831845f;

  float mx = s;
#pragma unroll
  for (int off = 8; off; off >>= 1) mx = fmaxf(mx, __shfl_xor(mx, off, 16));
  float ex = __expf(s - mx);
  float sum = ex;
#pragma unroll
  for (int off = 8; off; off >>= 1) sum += __shfl_xor(sum, off, 16);
  float a = ex / sum;

  attnOut[(size_t)p * 256 + t] = a;
  sc[t] = a;
  __syncthreads();

  const int dh0 = j * 8;
  float o[8] = {};
#pragma unroll
  for (int jjq = 0; jjq < 16; ++jjq) {
    float aij = sc[i * 16 + jjq];
#pragma unroll
    for (int e2 = 0; e2 < 8; ++e2)
      o[e2] = fmaf(aij, vf[jjq * 128 + dh0 + e2], o[e2]);
  }
  const int b = p >> 12, spos = p & 4095;
  const int row = i * 256 + (spos >> 4);
  const int col = ((spos & 15) << 7) + dh0;
  ushort8 pk;
#pragma unroll
  for (int e2 = 0; e2 < 8; ++e2) pk[e2] = f2bf(o[e2]);
  *(ushort8*)(X2 + (size_t)b * (SEQ * DIM) + (size_t)row * DIM + col) = pk;
}

// ---------------------------------------------------------------------------
extern "C" void kernel_launch(void* const* d_in, const int* in_sizes, int n_in,
                              void* d_out, int out_size, void* d_ws,
                              size_t ws_size, hipStream_t stream) {
  const float* q  = (const float*)d_in[0];
  const float* k  = (const float*)d_in[1];
  const float* v  = (const float*)d_in[2];
  const float* Wq = (const float*)d_in[3];
  const float* bq = (const float*)d_in[4];
  const float* Wk = (const float*)d_in[5];
  const float* bk = (const float*)d_in[6];
  const float* Wv = (const float*)d_in[7];
  const float* bv = (const float*)d_in[8];
  const float* Wo = (const float*)d_in[9];
  const float* bo = (const float*)d_in[10];

  const size_t NE = (size_t)GM * GK;  // 33,554,432
  const size_t WE = (size_t)GK * GN;  //  4,194,304

  unsigned short* ws16 = (unsigned short*)d_ws;
  unsigned short* Wq_b = ws16;
  unsigned short* Wk_b = Wq_b + WE;
  unsigned short* Wv_b = Wk_b + WE;
  unsigned short* Wo_b = Wv_b + WE;
  unsigned short* Qb   = Wo_b + WE;
  unsigned short* Kb   = Qb + NE;
  unsigned short* Vb   = Kb + NE;
  unsigned short* X2   = Vb + NE;

  float* outMain = (float*)d_out;
  float* attnOut = outMain + (size_t)GM * GN;

  cvt_f32_bf16<<<WE / 1024, 256, 0, stream>>>(Wq, Wq_b, (int)WE);
  cvt_f32_bf16<<<WE / 1024, 256, 0, stream>>>(Wk, Wk_b, (int)WE);
  cvt_f32_bf16<<<WE / 1024, 256, 0, stream>>>(Wv, Wv_b, (int)WE);
  cvt_f32_bf16<<<WE / 1024, 256, 0, stream>>>(Wo, Wo_b, (int)WE);

  constexpr int G256 = (GM / 256) * (GN / 256);   // 512

  // Q/K/V projections with fused fp32->bf16 A conversion
  gemm256<true, false><<<G256, 512, 0, stream>>>(q, Wq_b, bq, Qb);
  gemm256<true, false><<<G256, 512, 0, stream>>>(k, Wk_b, bk, Kb);
  gemm256<true, false><<<G256, 512, 0, stream>>>(v, Wv_b, bv, Vb);

  attn_kernel<<<GM, 256, 0, stream>>>(Qb, Kb, Vb, attnOut, X2);

  gemm256<false, true><<<G256, 512, 0, stream>>>(X2, Wo_b, bo, outMain);
}

// Round 4
// 822.236 us; speedup vs baseline: 1.3056x; 1.3056x over previous
//
#include <hip/hip_runtime.h>

// ---------------------------------------------------------------------------
// MHSA (faithful: softmax over HEADS at each position).
//   cvt: fp32->bf16 for weights + activations (roofline ~38us each)
//   GEMM: 256x256 8-wave, 4 quadrant-phases/K-tile, ds_reads hidden under
//         previous MFMA cluster (reg reuse), 3 barriers/tile, counted vmcnt
//   attention: per-position 16x16 softmax-over-heads + PV, permuted scatter
// ---------------------------------------------------------------------------

#define DEV __device__ __forceinline__

using short8  = __attribute__((ext_vector_type(8))) short;
using ushort8 = __attribute__((ext_vector_type(8))) unsigned short;
using f32x4   = __attribute__((ext_vector_type(4))) float;
using u16x8   = __attribute__((ext_vector_type(8))) unsigned short;

constexpr int BATCH = 4, SEQ = 4096, DIM = 2048;
constexpr int GM = BATCH * SEQ;   // 16384
constexpr int GN = DIM, GK = DIM; // 2048

DEV unsigned short f2bf(float f) {
  unsigned int u = __builtin_bit_cast(unsigned int, f);
  u += 0x7FFFu + ((u >> 16) & 1u);   // RNE
  return (unsigned short)(u >> 16);
}
DEV float bf2f(unsigned short h) {
  unsigned int u = ((unsigned int)h) << 16;
  return __builtin_bit_cast(float, u);
}

DEV void gload16(const void* g, void* l) {
  __builtin_amdgcn_global_load_lds(
      (const __attribute__((address_space(1))) void*)g,
      (__attribute__((address_space(3))) void*)l, 16, 0, 0);
}

#define BAR    __builtin_amdgcn_s_barrier()
#define LGKM0  asm volatile("s_waitcnt lgkmcnt(0)" ::: "memory")
#define VMC(N) asm volatile("s_waitcnt vmcnt(" #N ")" ::: "memory")
#define SCHED0 __builtin_amdgcn_sched_barrier(0)
#define PRIO1  __builtin_amdgcn_s_setprio(1)
#define PRIO0  __builtin_amdgcn_s_setprio(0)
#define MFMA16(a, b, c) __builtin_amdgcn_mfma_f32_16x16x32_bf16(a, b, c, 0, 0, 0)

// ---------------- fp32 -> bf16 conversion ---------------------------------
__global__ void cvt_f32_bf16(const float* __restrict__ src,
                             unsigned short* __restrict__ dst, int n) {
  int i = (blockIdx.x * blockDim.x + threadIdx.x) * 4;
  if (i >= n) return;
  f32x4 f = *(const f32x4*)(src + i);
  ushort4 o;
  o.x = f2bf(f[0]); o.y = f2bf(f[1]); o.z = f2bf(f[2]); o.w = f2bf(f[3]);
  *(ushort4*)(dst + i) = o;
}

// ---------------- 256^2 8-wave GEMM: C = A[M,K] * B[N,K]^T + bias ---------
// LDS: 2x(A 256x64 + B 256x64) bf16 = 128 KiB, XOR-swizzled (byte^=(row&7)<<4).
// Per K-tile: 4 quadrant phases x 16 MFMA; all ds_reads issued AFTER the
// MFMA cluster that frees their destination regs (overlap LDS pipe w/ matrix
// pipe); 3 barriers/tile; vmcnt(4) steady-state (vmcnt(0) for last 2 tiles).
template <bool OUTF32>
__global__ __launch_bounds__(512, 2)
void gemm256(const unsigned short* __restrict__ Ap,
             const unsigned short* __restrict__ Bp,
             const float* __restrict__ bias, void* __restrict__ Cp) {
  constexpr int BK = 64, KT = GK / BK;   // 32 K-tiles
  __shared__ unsigned short As[2][256 * BK];
  __shared__ unsigned short Bs[2][256 * BK];

  const int tid  = threadIdx.x;
  const int lane = tid & 63;
  const int wv   = tid >> 6;
  const int wm   = wv >> 2, wn = wv & 3;

  // XCD-chunked mapping: xcd owns mt stripe [xcd*8, xcd*8+8); concurrent
  // window 4mt x 8nt per XCD (proven: FETCH 270->131 MB).
  int bid = (int)blockIdx.x;
  const int xcd = bid & 7, rr = bid >> 3;
  const int gg = rr >> 5, jj = rr & 31;
  const int mt = xcd * 8 + gg * 4 + (jj & 3);
  const int nt = jj >> 2;
  const int bm0 = mt * 256, bn0 = nt * 256;

  // staging geometry: dest byte d (linear), source elem = unswizzle(d)
  const int dst0 = tid * 16;
  int offA[4], offB[4];
#pragma unroll
  for (int r = 0; r < 4; ++r) {
    int d = dst0 + r * 8192;
    int s = d ^ (((d >> 7) & 7) << 4);
    int row = s >> 7, col = (s & 127) >> 1;
    offA[r] = (bm0 + row) * GK + col;
    offB[r] = (bn0 + row) * GK + col;
  }

  const int r16 = lane & 15, kb = (lane >> 4) * 16;
  const int arow = wm * 128 + r16;
  const int brow = wn * 64 + r16;

  f32x4 acc[8][4] = {};
  short8 af[4][2], bl[2][2], bh[2][2];

  auto stA = [&](int buf, int kt, int r) {
    gload16(Ap + (size_t)offA[r] + (size_t)kt * BK,
            (char*)&As[buf][0] + (dst0 + r * 8192));
  };
  auto stB = [&](int buf, int kt, int r) {
    gload16(Bp + (size_t)offB[r] + (size_t)kt * BK,
            (char*)&Bs[buf][0] + (dst0 + r * 8192));
  };
  auto ldf = [&](const unsigned short* base, int row, int ks) -> short8 {
    int a = (row * 128 + ks * 64 + kb) ^ ((row & 7) << 4);
    return *(const short8*)((const char*)base + a);
  };

  // ---- prologue: A(0),B(0) -> buf0 ; A(1) -> buf1 ----
#pragma unroll
  for (int r = 0; r < 4; ++r) stA(0, 0, r);
#pragma unroll
  for (int r = 0; r < 4; ++r) stB(0, 0, r);
#pragma unroll
  for (int r = 0; r < 4; ++r) stA(1, 1, r);
  VMC(4);   // A(0)+B(0) resident; A(1) in flight
  BAR;
  // preload tile-0 fragments (af_lo, bl)
#pragma unroll
  for (int m = 0; m < 4; ++m) {
    af[m][0] = ldf(&As[0][0], arow + m * 16, 0);
    af[m][1] = ldf(&As[0][0], arow + m * 16, 1);
  }
#pragma unroll
  for (int n = 0; n < 2; ++n) {
    bl[n][0] = ldf(&Bs[0][0], brow + n * 16, 0);
    bl[n][1] = ldf(&Bs[0][0], brow + n * 16, 1);
  }

  for (int kt = 0; kt < KT; ++kt) {
    const int cb = kt & 1, nb = cb ^ 1;
    const unsigned short* Ab = &As[cb][0];
    const unsigned short* Bb = &Bs[cb][0];
    const unsigned short* An = &As[nb][0];
    const unsigned short* Bn = &Bs[nb][0];
    const bool m1 = (kt + 1 < KT), m2 = (kt + 2 < KT);

    // ===== P0: Q(mlo,nlo) ; post-reads: bh =====
    if (m1) { stB(nb, kt + 1, 0); stB(nb, kt + 1, 1); }
    LGKM0; SCHED0;
    PRIO1;
#pragma unroll
    for (int m = 0; m < 4; ++m)
#pragma unroll
      for (int n = 0; n < 2; ++n) {
        acc[m][n] = MFMA16(af[m][0], bl[n][0], acc[m][n]);
        acc[m][n] = MFMA16(af[m][1], bl[n][1], acc[m][n]);
      }
#pragma unroll
    for (int n = 0; n < 2; ++n) {
      bh[n][0] = ldf(Bb, brow + 32 + n * 16, 0);
      bh[n][1] = ldf(Bb, brow + 32 + n * 16, 1);
    }
    PRIO0; SCHED0;
    // (no barrier: stB targets nb; cb readers unaffected)

    // ===== P1: Q(mlo,nhi) ; post-reads: af <- A-hi =====
    if (m1) { stB(nb, kt + 1, 2); stB(nb, kt + 1, 3); }
    LGKM0; SCHED0;
    PRIO1;
#pragma unroll
    for (int m = 0; m < 4; ++m)
#pragma unroll
      for (int n = 0; n < 2; ++n) {
        acc[m][2 + n] = MFMA16(af[m][0], bh[n][0], acc[m][2 + n]);
        acc[m][2 + n] = MFMA16(af[m][1], bh[n][1], acc[m][2 + n]);
      }
#pragma unroll
    for (int m = 0; m < 4; ++m) {
      af[m][0] = ldf(Ab, arow + 64 + m * 16, 0);
      af[m][1] = ldf(Ab, arow + 64 + m * 16, 1);
    }
    PRIO0; SCHED0;
    BAR;   // BAR1: all waves' af_lo reads done (pre-Q0 lgkm) -> stA lo safe

    // ===== P2: Q(mhi,nhi) =====
    if (m2) { stA(cb, kt + 2, 0); stA(cb, kt + 2, 2); }   // lo rows
    LGKM0; SCHED0;
    PRIO1;
#pragma unroll
    for (int m = 0; m < 4; ++m)
#pragma unroll
      for (int n = 0; n < 2; ++n) {
        acc[4 + m][2 + n] = MFMA16(af[m][0], bh[n][0], acc[4 + m][2 + n]);
        acc[4 + m][2 + n] = MFMA16(af[m][1], bh[n][1], acc[4 + m][2 + n]);
      }
    PRIO0; SCHED0;
    BAR;   // BAR2: all waves' af_hi reads done (pre-Q2 lgkm) -> stA hi safe

    // ===== P3: Q(mhi,nlo) ; post-reads: next tile af_lo, bl =====
    if (m2) { stA(cb, kt + 2, 1); stA(cb, kt + 2, 3); }   // hi rows
    if (m2) { VMC(4); } else { VMC(0); }   // drain A(t+1)+B(t+1) (all, at tail)
    SCHED0;
    BAR;   // BAR3: next-tile buffers (nb) staged & visible to all waves
    PRIO1;
#pragma unroll
    for (int m = 0; m < 4; ++m)
#pragma unroll
      for (int n = 0; n < 2; ++n) {
        acc[4 + m][n] = MFMA16(af[m][0], bl[n][0], acc[4 + m][n]);
        acc[4 + m][n] = MFMA16(af[m][1], bl[n][1], acc[4 + m][n]);
      }
    if (m1) {
#pragma unroll
      for (int m = 0; m < 4; ++m) {
        af[m][0] = ldf(An, arow + m * 16, 0);
        af[m][1] = ldf(An, arow + m * 16, 1);
      }
#pragma unroll
      for (int n = 0; n < 2; ++n) {
        bl[n][0] = ldf(Bn, brow + n * 16, 0);
        bl[n][1] = ldf(Bn, brow + n * 16, 1);
      }
    }
    PRIO0; SCHED0;
  }

  // ---- epilogue: C row=(lane>>4)*4+i, col=lane&15 (m89-verified) ----
  float bs[4];
#pragma unroll
  for (int n = 0; n < 4; ++n) bs[n] = bias[bn0 + wn * 64 + n * 16 + r16];
  const int rb = (lane >> 4) * 4;
#pragma unroll
  for (int m = 0; m < 8; ++m)
#pragma unroll
    for (int i = 0; i < 4; ++i) {
      const size_t row = (size_t)bm0 + wm * 128 + m * 16 + rb + i;
#pragma unroll
      for (int n = 0; n < 4; ++n) {
        const int col = bn0 + wn * 64 + n * 16 + r16;
        float v = acc[m][n][i] + bs[n];
        if constexpr (OUTF32)
          ((float*)Cp)[row * GN + col] = v;
        else
          ((unsigned short*)Cp)[row * GN + col] = f2bf(v);
      }
    }
}

// ---------------- per-position attention (softmax over heads) -------------
__global__ __launch_bounds__(256)
void attn_kernel(const unsigned short* __restrict__ Qb,
                 const unsigned short* __restrict__ Kb,
                 const unsigned short* __restrict__ Vb,
                 float* __restrict__ attnOut,
                 unsigned short* __restrict__ X2) {
  __shared__ float qf[16 * 128];
  __shared__ float kf[16 * 132];
  __shared__ float vf[16 * 128];
  __shared__ float sc[256];

  const int t = threadIdx.x;
  const int p = blockIdx.x;
  const size_t rowoff = (size_t)p * DIM;

  {
    const int e = t * 8;
    u16x8 qv = *(const u16x8*)(Qb + rowoff + e);
    u16x8 kv = *(const u16x8*)(Kb + rowoff + e);
    u16x8 vv = *(const u16x8*)(Vb + rowoff + e);
    const int r = t >> 4, c = (t & 15) * 8;
#pragma unroll
    for (int j = 0; j < 8; ++j) qf[r * 128 + c + j] = bf2f(qv[j]);
#pragma unroll
    for (int j = 0; j < 8; ++j) kf[r * 132 + c + j] = bf2f(kv[j]);
#pragma unroll
    for (int j = 0; j < 8; ++j) vf[r * 128 + c + j] = bf2f(vv[j]);
  }
  __syncthreads();

  const int i = t >> 4, j = t & 15;
  float s = 0.f;
#pragma unroll
  for (int d4 = 0; d4 < 32; ++d4) {
    f32x4 q4 = *(const f32x4*)&qf[i * 128 + d4 * 4];
    f32x4 k4 = *(const f32x4*)&kf[j * 132 + d4 * 4];
    s = fmaf(q4[0], k4[0], fmaf(q4[1], k4[1], fmaf(q4[2], k4[2], fmaf(q4[3], k4[3], s))));
  }
  s *= 0.08838834764831845f;

  float mx = s;
#pragma unroll
  for (int off = 8; off; off >>= 1) mx = fmaxf(mx, __shfl_xor(mx, off, 16));
  float ex = __expf(s - mx);
  float sum = ex;
#pragma unroll
  for (int off = 8; off; off >>= 1) sum += __shfl_xor(sum, off, 16);
  float a = ex / sum;

  attnOut[(size_t)p * 256 + t] = a;
  sc[t] = a;
  __syncthreads();

  const int dh0 = j * 8;
  float o[8] = {};
#pragma unroll
  for (int jjq = 0; jjq < 16; ++jjq) {
    float aij = sc[i * 16 + jjq];
#pragma unroll
    for (int e2 = 0; e2 < 8; ++e2)
      o[e2] = fmaf(aij, vf[jjq * 128 + dh0 + e2], o[e2]);
  }
  const int b = p >> 12, spos = p & 4095;
  const int row = i * 256 + (spos >> 4);
  const int col = ((spos & 15) << 7) + dh0;
  ushort8 pk;
#pragma unroll
  for (int e2 = 0; e2 < 8; ++e2) pk[e2] = f2bf(o[e2]);
  *(ushort8*)(X2 + (size_t)b * (SEQ * DIM) + (size_t)row * DIM + col) = pk;
}

// ---------------------------------------------------------------------------
extern "C" void kernel_launch(void* const* d_in, const int* in_sizes, int n_in,
                              void* d_out, int out_size, void* d_ws,
                              size_t ws_size, hipStream_t stream) {
  const float* q  = (const float*)d_in[0];
  const float* k  = (const float*)d_in[1];
  const float* v  = (const float*)d_in[2];
  const float* Wq = (const float*)d_in[3];
  const float* bq = (const float*)d_in[4];
  const float* Wk = (const float*)d_in[5];
  const float* bk = (const float*)d_in[6];
  const float* Wv = (const float*)d_in[7];
  const float* bv = (const float*)d_in[8];
  const float* Wo = (const float*)d_in[9];
  const float* bo = (const float*)d_in[10];

  const size_t NE = (size_t)GM * GK;  // 33,554,432
  const size_t WE = (size_t)GK * GN;  //  4,194,304

  unsigned short* ws16 = (unsigned short*)d_ws;
  unsigned short* Wq_b = ws16;
  unsigned short* Wk_b = Wq_b + WE;
  unsigned short* Wv_b = Wk_b + WE;
  unsigned short* Wo_b = Wv_b + WE;
  unsigned short* Qb   = Wo_b + WE;
  unsigned short* Kb   = Qb + NE;
  unsigned short* Vb   = Kb + NE;
  unsigned short* X2   = Vb + NE;
  unsigned short* Qin  = X2 + NE;
  unsigned short* Kin  = Qin + NE;
  unsigned short* Vin  = Kin + NE;

  float* outMain = (float*)d_out;
  float* attnOut = outMain + (size_t)GM * GN;

  cvt_f32_bf16<<<WE / 1024, 256, 0, stream>>>(Wq, Wq_b, (int)WE);
  cvt_f32_bf16<<<WE / 1024, 256, 0, stream>>>(Wk, Wk_b, (int)WE);
  cvt_f32_bf16<<<WE / 1024, 256, 0, stream>>>(Wv, Wv_b, (int)WE);
  cvt_f32_bf16<<<WE / 1024, 256, 0, stream>>>(Wo, Wo_b, (int)WE);

  cvt_f32_bf16<<<NE / 1024, 256, 0, stream>>>(q, Qin, (int)NE);
  cvt_f32_bf16<<<NE / 1024, 256, 0, stream>>>(k, Kin, (int)NE);
  cvt_f32_bf16<<<NE / 1024, 256, 0, stream>>>(v, Vin, (int)NE);

  constexpr int G256 = (GM / 256) * (GN / 256);   // 512

  gemm256<false><<<G256, 512, 0, stream>>>(Qin, Wq_b, bq, Qb);
  gemm256<false><<<G256, 512, 0, stream>>>(Kin, Wk_b, bk, Kb);
  gemm256<false><<<G256, 512, 0, stream>>>(Vin, Wv_b, bv, Vb);

  attn_kernel<<<GM, 256, 0, stream>>>(Qb, Kb, Vb, attnOut, X2);

  gemm256<true><<<G256, 512, 0, stream>>>(X2, Wo_b, bo, outMain);
}